// Round 1
// 399.572 us; speedup vs baseline: 1.0332x; 1.0332x over previous
//
#include <hip/hip_runtime.h>
#include <hip/hip_bf16.h>
#include <stdint.h>

#define DIM 256
#define TOPK 8
#define NSTRIPS 64
#define STRIP_TOP 8                  // per (query,strip) top-8
#define QT 256
#define NT 64
#define CAND (NSTRIPS * STRIP_TOP)   // 512
#define RESCORE 64
#define SLOTS 33                     // u32 row stride for packed scores
#define IDXMASK 0x1FFFFu

typedef __attribute__((ext_vector_type(8))) short short8;
typedef __attribute__((ext_vector_type(4))) float floatx4;
typedef __attribute__((address_space(3))) unsigned int lds_u32;
typedef __attribute__((address_space(1))) const unsigned int gbl_u32;

__device__ __forceinline__ unsigned short f2bf(float f) {
    union { float f; uint32_t u; } v; v.f = f;
    uint32_t u = v.u;
    uint32_t r = u + 0x7fffu + ((u >> 16) & 1u);   // RNE
    return (unsigned short)(r >> 16);
}

__device__ __forceinline__ uint32_t umaxu(uint32_t a, uint32_t b) { return a > b ? a : b; }
__device__ __forceinline__ uint32_t uminu(uint32_t a, uint32_t b) { return a < b ? a : b; }

// sorted-ascending top-8 insert: new[j] = med3(old[j], old[j+1], key); new[7]=max
__device__ __forceinline__ void top8_insert(uint32_t* ts, uint32_t key) {
#pragma unroll
    for (int j = 0; j < STRIP_TOP - 1; j++) {
        uint32_t m;
        asm("v_med3_u32 %0, %1, %2, %3" : "=v"(m) : "v"(ts[j]), "v"(ts[j + 1]), "v"(key));
        ts[j] = m;
    }
    ts[STRIP_TOP - 1] = umaxu(ts[STRIP_TOP - 1], key);
}

// ---------------- Kernel 1: norms + normalized bf16 copies ----------------
__global__ void prep_kernel(const float* __restrict__ query,
                            const float* __restrict__ mem,
                            float* __restrict__ rnorm_mem,
                            unsigned short* __restrict__ q_bf16,
                            unsigned short* __restrict__ mem_bf16,  // may be null
                            int B, int N)
{
    int wave = threadIdx.x >> 6;
    int lane = threadIdx.x & 63;
    int row  = blockIdx.x * 4 + wave;
    int total = N + B;
    if (row >= total) return;
    const float* src = (row < N) ? (mem + (size_t)row * DIM)
                                 : (query + (size_t)(row - N) * DIM);
    float4 v = ((const float4*)src)[lane];
    float ss = v.x * v.x + v.y * v.y + v.z * v.z + v.w * v.w;
#pragma unroll
    for (int m = 32; m >= 1; m >>= 1) ss += __shfl_xor(ss, m, 64);
    float rinv = 1.0f / fmaxf(sqrtf(ss), 1e-12f);
    ushort4 o;
    o.x = f2bf(v.x * rinv); o.y = f2bf(v.y * rinv);
    o.z = f2bf(v.z * rinv); o.w = f2bf(v.w * rinv);
    if (row < N) {
        if (lane == 0) rnorm_mem[row] = rinv;
        if (mem_bf16) ((ushort4*)(mem_bf16 + (size_t)row * DIM))[lane] = o;
    } else {
        ((ushort4*)(q_bf16 + (size_t)(row - N) * DIM))[lane] = o;
    }
}

// ---------------- Kernel 2: bf16-MFMA scoring + gated top-8 ----------------
// 8-wave version: 512 threads, each wave owns 2 A-sets (32 query rows).
// Occupancy: LDS 66560 B -> 2 blocks/CU -> 16 waves/CU (4/SIMD), 2x the 4-wave version.
// XCD swizzle: the 8 query-blocks sharing a strip map to ONE XCD (strip data 800 KB < 4 MB L2).
template<bool PRE>
__global__ __launch_bounds__(512, 4) void score_select_kernel(
    const float* __restrict__ mem,
    const float* __restrict__ rnorm_mem,
    const unsigned short* __restrict__ mem_bf16,
    const unsigned short* __restrict__ q_bf16,
    uint32_t* __restrict__ cand_key,
    int B, int N)
{
    __shared__ unsigned short lds_m[NT * DIM];     // 32768 B, XOR-swizzled rows
    __shared__ uint32_t lds_s[QT * SLOTS];         // 33792 B: [q][slot j] = (lo=col j, hi=col j+32)

    const int t    = threadIdx.x;
    const int wave = t >> 6;                       // 0..7
    const int lane = t & 63;
    const int quad = lane >> 4;
    const int l16  = lane & 15;

    // XCD-bijective block swizzle: lin -> (xcd, withinXcd); all 8 qb-peers of a
    // strip share lin&7 (same XCD under round-robin dispatch).
    const int lin  = (int)(blockIdx.x + gridDim.x * blockIdx.y);
    const int SPX  = NSTRIPS / 8;                  // strips per XCD = 8
    const int strip = (lin & 7) * SPX + ((lin >> 3) % SPX);
    const int qb    = (lin >> 3) / SPX;
    const int qbase = qb * QT;

    const int SS    = (N + NSTRIPS - 1) / NSTRIPS;
    const int n0    = strip * SS;
    const int nend  = (n0 + SS < N) ? (n0 + SS) : N;
    const int limit = nend - n0;                    // valid strip-local rows
    const int ntiles = (limit + NT - 1) / NT;

    // Two A-sets per wave: q rows  qbase + s*128 + wave*16 + l16,  full K=256.
    short8 afrag[2][8];
#pragma unroll
    for (int s = 0; s < 2; s++) {
        int qrow = qbase + s * 128 + wave * 16 + l16;
        const unsigned short* qp = q_bf16 + (size_t)qrow * DIM + quad * 8;
#pragma unroll
        for (int ks = 0; ks < 8; ks++)
            afrag[s][ks] = *(const short8*)(qp + ks * 32);
    }

    // per-thread top-8 keys (ascending). Thread t owns query (t&255), its HALF
    // (t>>8) of the 32 packed u32 slots; halves merged exactly in the epilogue.
    uint32_t ts[STRIP_TOP];
#pragma unroll
    for (int j = 0; j < STRIP_TOP; j++) ts[j] = 0;

    const int l5  = lane >> 5;   // 0/1
    const int s32 = lane & 31;

    auto stage = [&](int tileIdx) {
        int base = n0 + tileIdx * NT;
        if (PRE) {
#pragma unroll
            for (int is = 0; is < 4; is++) {
                int rl = is * 16 + wave * 2 + l5;
                int n = base + rl; if (n >= nend) n = nend - 1;
                int chunk = s32 ^ (rl & 7);
                const unsigned short* gp = mem_bf16 + (size_t)n * DIM + chunk * 8;
                unsigned short* lp = lds_m + (is * 16 + wave * 2) * DIM;  // wave-uniform
                __builtin_amdgcn_global_load_lds((gbl_u32*)(const void*)gp,
                                                 (lds_u32*)(void*)lp, 16, 0, 0);
            }
        } else {
#pragma unroll 4
            for (int i = 0; i < 8; i++) {
                int rl = i * 8 + wave;
                int n = base + rl;
                ushort4 o;
                if (n < nend) {
                    float rinv = rnorm_mem[n];
                    float4 v = ((const float4*)(mem + (size_t)n * DIM))[lane];
                    o.x = f2bf(v.x * rinv); o.y = f2bf(v.y * rinv);
                    o.z = f2bf(v.z * rinv); o.w = f2bf(v.w * rinv);
                } else { o.x = 0; o.y = 0; o.z = 0; o.w = 0; }
                int slot = (lane >> 1) ^ (rl & 7);
                *(ushort4*)(lds_m + rl * DIM + slot * 8 + (lane & 1) * 4) = o;
            }
        }
    };

    stage(0);
    __syncthreads();

    const int qloc = t & 255;
    const int half = t >> 8;

    const floatx4 one4 = {1.f, 1.f, 1.f, 1.f};   // bias: D = q·m + 1 >= 0 -> raw bits monotone
    for (int tile = 0; tile < ntiles; tile++) {
        floatx4 acc[2][4];
#pragma unroll
        for (int s = 0; s < 2; s++)
#pragma unroll
            for (int nt = 0; nt < 4; nt++) acc[s][nt] = one4;

#pragma unroll
        for (int ks = 0; ks < 8; ks++) {
#pragma unroll
            for (int nt = 0; nt < 4; nt++) {
                int row = nt * 16 + l16;
                int slot = (ks * 4 + quad) ^ (l16 & 7);
                short8 b = *(const short8*)(lds_m + row * DIM + slot * 8);
#pragma unroll
                for (int s = 0; s < 2; s++)
                    acc[s][nt] = __builtin_amdgcn_mfma_f32_16x16x32_bf16(afrag[s][ks], b, acc[s][nt], 0, 0, 0);
            }
        }
        // C layout: col(lane&15)=n, row(quad*4+r)=q.
        // Biased scores >= 0: top-16 raw bits are the monotone key halves.
#pragma unroll
        for (int s = 0; s < 2; s++) {
            int qrow = s * 128 + wave * 16 + quad * 4;
#pragma unroll
            for (int r = 0; r < 4; r++) {
                uint32_t u0 = __float_as_uint(fmaxf(acc[s][0][r], 0.f));
                uint32_t u1 = __float_as_uint(fmaxf(acc[s][1][r], 0.f));
                uint32_t u2 = __float_as_uint(fmaxf(acc[s][2][r], 0.f));
                uint32_t u3 = __float_as_uint(fmaxf(acc[s][3][r], 0.f));
                lds_s[(qrow + r) * SLOTS + l16]      = (u2 & 0xFFFF0000u) | (u0 >> 16);  // cols l16, l16+32
                lds_s[(qrow + r) * SLOTS + 16 + l16] = (u3 & 0xFFFF0000u) | (u1 >> 16);  // cols 16+l16, 48+l16
            }
        }
        __syncthreads();                     // scores visible; lds_m reads retired

        if (tile + 1 < ntiles) stage(tile + 1);  // overlaps with selection below

        // selection: thread owns query qloc, slots [half*16, half*16+16)
        // key = score16<<16 | loc ; u32 slot j packs cols (j, j+32)
        const int tloc = tile * NT;
        const uint4* sp = (const uint4*)(lds_s + (size_t)qloc * SLOTS + half * 16);
        bool full = (tloc + NT <= limit);
#pragma unroll
        for (int j4 = 0; j4 < 4; j4++) {
            uint4 v4 = sp[j4];
#pragma unroll
            for (int e = 0; e < 4; e++) {
                uint32_t v = (e == 0) ? v4.x : (e == 1) ? v4.y : (e == 2) ? v4.z : v4.w;
                int j = half * 16 + j4 * 4 + e;
                uint32_t key_lo = (v << 16) | (uint32_t)(tloc + j);
                uint32_t key_hi = (v & 0xFFFF0000u) | (uint32_t)(tloc + j + 32);
                if (!full) {
                    if (tloc + j >= limit)      key_lo = 0;
                    if (tloc + j + 32 >= limit) key_hi = 0;
                }
                uint32_t kmax = umaxu(key_lo, key_hi);
                uint32_t kmin = uminu(key_lo, key_hi);
                if (__any(kmax > ts[0])) {       // wave-gated: s_cbranch skips ripple
                    top8_insert(ts, kmax);        // no-op for non-qualifying lanes
                    if (__any(kmin > ts[0]))
                        top8_insert(ts, kmin);
                }
            }
        }
        __syncthreads();                     // selection + staging drained
    }

    // ---- merge the two halves' top-8 (exact), then write candidates ----
    if (half) {
#pragma unroll
        for (int j = 0; j < STRIP_TOP; j++) lds_s[qloc * SLOTS + j] = ts[j];
    }
    __syncthreads();
    if (!half) {
#pragma unroll
        for (int j = 0; j < STRIP_TOP; j++)
            top8_insert(ts, lds_s[qloc * SLOTS + j]);

        // convert to (score15 << 17 | gidx17) — proven key format
        size_t off = ((size_t)(qbase + qloc) * NSTRIPS + strip) * STRIP_TOP;
#pragma unroll
        for (int j = 0; j < STRIP_TOP; j++) {
            uint32_t k = ts[j];
            uint32_t loc = k & 0xFFFFu;
            uint32_t key2 = ((k >> 17) << 17) | (uint32_t)(n0 + (int)loc);
            cand_key[off + j] = key2;
        }
    }
}

// ---------------- Kernel 3: key sort, top-64 cut, fp64 rescore, top-8, gather ----------------
__global__ __launch_bounds__(256) void rescore_kernel(
    const float* __restrict__ query,
    const float* __restrict__ mem,
    const uint32_t* __restrict__ cand_key,
    float* __restrict__ out,
    int B, int N)
{
    __shared__ uint32_t cs[CAND];
    __shared__ float  lds_q[DIM];
    __shared__ double red[4];
    __shared__ double qss_sh;
    __shared__ int    sel_i[RESCORE];
    __shared__ double rs[RESCORE];
    __shared__ double best_s[TOPK];
    __shared__ int    best_i[TOPK];

    const int t    = threadIdx.x;
    const int q    = blockIdx.x;
    const int lane = t & 63;
    const int wave = t >> 6;

    for (int i = t; i < CAND; i += 256)
        cs[i] = cand_key[(size_t)q * CAND + i];

    float qv = query[(size_t)q * DIM + t];
    lds_q[t] = qv;
    double p = (double)qv * (double)qv;
#pragma unroll
    for (int m = 32; m >= 1; m >>= 1) p += __shfl_xor(p, m, 64);
    if (lane == 0) red[wave] = p;
    __syncthreads();
    if (t == 0) qss_sh = red[0] + red[1] + red[2] + red[3];

    // per-wave bitonic sort (descending) of its 128-key quarter; wave-synchronous
    {
        uint32_t* qcs = cs + wave * 128;
        for (int k = 2; k <= 128; k <<= 1) {
            for (int j = k >> 1; j > 0; j >>= 1) {
                int i  = 2 * lane - (lane & (j - 1));
                int ip = i + j;
                bool up = ((i & k) == 0);
                uint32_t a = qcs[i], b2 = qcs[ip];
                bool aFirst = a > b2;
                bool doSwap = up ? (!aFirst) : aFirst;
                if (doSwap) { qcs[i] = b2; qcs[ip] = a; }
            }
        }
        if (lane < 16) sel_i[wave * 16 + lane] = (int)(qcs[lane] & IDXMASK);
    }
    __syncthreads();

    // fp64 exact cosine for the 64 selected; each wave handles its 16
    double qss = qss_sh;
    for (int r = 0; r < 16; r++) {
        int c = wave * 16 + r;
        int idx = sel_i[c];
        float4 mv = ((const float4*)(mem + (size_t)idx * DIM))[lane];
        float4 qv4 = ((const float4*)lds_q)[lane];
        double dqm = (double)mv.x * (double)qv4.x + (double)mv.y * (double)qv4.y
                   + (double)mv.z * (double)qv4.z + (double)mv.w * (double)qv4.w;
        double dmm = (double)mv.x * (double)mv.x + (double)mv.y * (double)mv.y
                   + (double)mv.z * (double)mv.z + (double)mv.w * (double)mv.w;
#pragma unroll
        for (int m = 32; m >= 1; m >>= 1) {
            dqm += __shfl_xor(dqm, m, 64);
            dmm += __shfl_xor(dmm, m, 64);
        }
        if (lane == 0)
            rs[c] = dqm / (fmax(sqrt(qss), 1e-12) * fmax(sqrt(dmm), 1e-12));
    }
    __syncthreads();

    if (t == 0) {   // serial exact top-8, tie-break (score desc, idx asc)
        double bs[TOPK]; int bi[TOPK];
        for (int i = 0; i < TOPK; i++) { bs[i] = -1e300; bi[i] = 0x7fffffff; }
        for (int c = 0; c < RESCORE; c++) {
            double s = rs[c]; int id = sel_i[c];
            bool better = (s > bs[TOPK - 1]) || (s == bs[TOPK - 1] && id < bi[TOPK - 1]);
            if (better) {
                int pos = TOPK - 1;
                while (pos > 0) {
                    bool b2 = (s > bs[pos - 1]) || (s == bs[pos - 1] && id < bi[pos - 1]);
                    if (!b2) break;
                    bs[pos] = bs[pos - 1]; bi[pos] = bi[pos - 1]; pos--;
                }
                bs[pos] = s; bi[pos] = id;
            }
        }
        for (int i = 0; i < TOPK; i++) { best_s[i] = bs[i]; best_i[i] = bi[i]; }
    }
    __syncthreads();

    size_t score_base = (size_t)B * TOPK * DIM;
    if (t < TOPK) out[score_base + (size_t)q * TOPK + t] = (float)best_s[t];

#pragma unroll
    for (int rep = 0; rep < 2; rep++) {
        int j  = t >> 5;
        int d4 = (t & 31) + rep * 32;
        int idx = best_i[j];
        float4 v = ((const float4*)(mem + (size_t)idx * DIM))[d4];
        ((float4*)(out + ((size_t)q * TOPK + j) * DIM))[d4] = v;
    }
}

extern "C" void kernel_launch(void* const* d_in, const int* in_sizes, int n_in,
                              void* d_out, int out_size, void* d_ws, size_t ws_size,
                              hipStream_t stream)
{
    const float* query = (const float*)d_in[0];
    const float* mem   = (const float*)d_in[1];
    int B = in_sizes[0] / DIM;
    int N = in_sizes[1] / DIM;

    auto align256 = [](size_t x) { return (x + 255) & ~(size_t)255; };
    size_t off = 0;
    auto alloc = [&](size_t bytes) { void* p = (char*)d_ws + off; off += align256(bytes); return p; };

    float* rnorm_mem       = (float*)alloc((size_t)N * 4);
    unsigned short* q_bf16 = (unsigned short*)alloc((size_t)B * DIM * 2);
    uint32_t* cand_key     = (uint32_t*)alloc((size_t)B * CAND * 4);
    size_t base_need = off;
    unsigned short* mem_bf16 = (unsigned short*)((char*)d_ws + base_need);
    bool pre = (base_need + align256((size_t)N * DIM * 2)) <= ws_size;
    if (!pre) mem_bf16 = nullptr;

    int prep_blocks = (N + B + 3) / 4;
    prep_kernel<<<prep_blocks, 256, 0, stream>>>(query, mem, rnorm_mem, q_bf16,
                                                 mem_bf16, B, N);

    dim3 g2((B + QT - 1) / QT, NSTRIPS);
    if (pre)
        score_select_kernel<true><<<g2, 512, 0, stream>>>(mem, rnorm_mem, mem_bf16, q_bf16,
                                                          cand_key, B, N);
    else
        score_select_kernel<false><<<g2, 512, 0, stream>>>(mem, rnorm_mem, mem_bf16, q_bf16,
                                                           cand_key, B, N);

    rescore_kernel<<<B, 256, 0, stream>>>(query, mem, cand_key, (float*)d_out, B, N);
}